// Round 1
// baseline (607.705 us; speedup 1.0000x reference)
//
#include <hip/hip_runtime.h>
#include <stdint.h>

#define TOK 49
#define NTOK 100352      // 32*3136 tokens
#define K3 1152
#define C_DIM 384
#define NHEAD 12

typedef _Float16 half8 __attribute__((ext_vector_type(8)));
typedef float f32x4 __attribute__((ext_vector_type(4)));

__device__ __forceinline__ ushort f2h_bits(float f) {
  _Float16 h = (_Float16)f;
  return __builtin_bit_cast(ushort, h);
}

__device__ __forceinline__ void gload_lds16(const void* gp, void* lp) {
  __builtin_amdgcn_global_load_lds(
      (const __attribute__((address_space(1))) void*)gp,
      (__attribute__((address_space(3))) void*)lp, 16, 0, 0);
}

// ---------------- x fp32 -> fp16 ----------------
__global__ __launch_bounds__(256) void cvt_f32_f16(const float* __restrict__ in,
                                                   _Float16* __restrict__ out, int n4) {
  int i = blockIdx.x * 256 + threadIdx.x;
  if (i >= n4) return;
  float4 v = *((const float4*)in + i);
  ushort4 o;
  o.x = f2h_bits(v.x); o.y = f2h_bits(v.y); o.z = f2h_bits(v.z); o.w = f2h_bits(v.w);
  *((ushort4*)out + i) = o;
}

// ---------------- W [R][Cc] fp32 -> W^T [Cc][R] fp16 ----------------
__global__ __launch_bounds__(256) void transpose_to_f16(const float* __restrict__ in,
                                                        _Float16* __restrict__ out,
                                                        int R, int Cc) {
  int idx = blockIdx.x * 256 + threadIdx.x;
  if (idx >= R * Cc) return;
  int n = idx / R, k = idx - n * R;
  out[idx] = (_Float16)in[(size_t)k * Cc + n];
}

// ---------------- bias[h][q][k] = table[relidx[q][k]][h] ----------------
__global__ __launch_bounds__(256) void bias_expand(const float* __restrict__ table,
                                                   const int* __restrict__ relidx,
                                                   float* __restrict__ out) {
  int idx = blockIdx.x * 256 + threadIdx.x;
  if (idx >= NHEAD * TOK * TOK) return;
  int h = idx / (TOK * TOK);
  int qk = idx - h * (TOK * TOK);
  out[idx] = table[relidx[qk] * NHEAD + h];
}

// ---------------- GEMM: C[M][N] = A[M][K] @ Bt[N][K]^T + bias ----------------
// 128x128 tile, BK=32, 256 thr (4 waves 2x2), wave = 64x64 (4x4 frags 16x16x32)
template <int OUT_F32>
__global__ __launch_bounds__(256) void gemm_f16(const _Float16* __restrict__ A,
                                                const _Float16* __restrict__ Bt,
                                                const float* __restrict__ bias,
                                                void* __restrict__ Cout,
                                                int N, int K, int Ntiles) {
  __shared__ _Float16 As[128 * 32];
  __shared__ _Float16 Bs[128 * 32];
  int bid = blockIdx.x;
  int bm = bid / Ntiles, bn = bid - bm * Ntiles;
  int tid = threadIdx.x;
  int lane = tid & 63, wave = tid >> 6;
  int wm = wave >> 1, wn = wave & 1;

  int srow = tid >> 2;            // 0..63 staging row
  int scol = (tid & 3) * 8;       // fp16 col offset
  const _Float16* gA = A + (size_t)(bm * 128 + srow) * K + scol;
  const _Float16* gB = Bt + (size_t)(bn * 128 + srow) * K + scol;
  char* ldsA = (char*)As + wave * 1024;  // wave-uniform base; HW adds lane*16
  char* ldsB = (char*)Bs + wave * 1024;

  f32x4 acc[4][4];
#pragma unroll
  for (int m = 0; m < 4; m++)
#pragma unroll
    for (int n = 0; n < 4; n++) acc[m][n] = (f32x4){0.f, 0.f, 0.f, 0.f};

  int fr = lane & 15;
  int fk = (lane >> 4) * 8;

  for (int k0 = 0; k0 < K; k0 += 32) {
    __syncthreads();
    gload_lds16(gA + k0, ldsA);
    gload_lds16(gA + (size_t)64 * K + k0, ldsA + 4096);
    gload_lds16(gB + k0, ldsB);
    gload_lds16(gB + (size_t)64 * K + k0, ldsB + 4096);
    __syncthreads();
    half8 af[4], bf[4];
#pragma unroll
    for (int m = 0; m < 4; m++)
      af[m] = *(const half8*)(As + (wm * 64 + m * 16 + fr) * 32 + fk);
#pragma unroll
    for (int n = 0; n < 4; n++)
      bf[n] = *(const half8*)(Bs + (wn * 64 + n * 16 + fr) * 32 + fk);
#pragma unroll
    for (int m = 0; m < 4; m++)
#pragma unroll
      for (int n = 0; n < 4; n++)
        acc[m][n] = __builtin_amdgcn_mfma_f32_16x16x32_f16(af[m], bf[n], acc[m][n], 0, 0, 0);
  }

  int rowbase = bm * 128 + wm * 64;
  int colbase = bn * 128 + wn * 64;
#pragma unroll
  for (int n = 0; n < 4; n++) {
    int col = colbase + n * 16 + fr;
    float bb = bias[col];
#pragma unroll
    for (int m = 0; m < 4; m++) {
      int row0 = rowbase + m * 16 + (lane >> 4) * 4;
#pragma unroll
      for (int r = 0; r < 4; r++) {
        float v = acc[m][n][r] + bb;
        if (OUT_F32)
          ((float*)Cout)[(size_t)(row0 + r) * N + col] = v;
        else
          ((ushort*)Cout)[(size_t)(row0 + r) * N + col] = f2h_bits(v);
      }
    }
  }
}

// ---------------- window attention: 1 wave per (window, head) ----------------
__global__ __launch_bounds__(256) void win_attn(const _Float16* __restrict__ qkv,
                                                const float* __restrict__ biasf,
                                                _Float16* __restrict__ aout) {
  __shared__ _Float16 P[4][64 * 72];   // per-wave P tile, padded stride 72
  int lane = threadIdx.x & 63, wave = threadIdx.x >> 6;
  int id = blockIdx.x * 4 + wave;      // 0..24575
  int win = id / NHEAD;
  int h = id - win * NHEAD;
  const _Float16* base = qkv + (size_t)win * TOK * K3 + h * 32;
  int fr = lane & 15, fg = lane >> 4;

  // Q/K fragments straight from global (row = fr within 16-tile, 8 contig k)
  half8 qf[4], kf[4];
#pragma unroll
  for (int i = 0; i < 4; i++) {
    int q = i * 16 + fr;
    qf[i] = (half8){0, 0, 0, 0, 0, 0, 0, 0};
    kf[i] = (half8){0, 0, 0, 0, 0, 0, 0, 0};
    if (q < TOK) {
      qf[i] = *(const half8*)(base + (size_t)q * K3 + fg * 8);
      kf[i] = *(const half8*)(base + (size_t)q * K3 + 384 + fg * 8);
    }
  }

  f32x4 s[4][4];
#pragma unroll
  for (int i = 0; i < 4; i++)
#pragma unroll
    for (int j = 0; j < 4; j++) s[i][j] = (f32x4){0.f, 0.f, 0.f, 0.f};
#pragma unroll
  for (int i = 0; i < 4; i++)
#pragma unroll
    for (int j = 0; j < 4; j++)
      s[i][j] = __builtin_amdgcn_mfma_f32_16x16x32_f16(qf[i], kf[j], s[i][j], 0, 0, 0);

  const float scale = 0.17677669529663687f;
  const float* bh = biasf + h * (TOK * TOK);
#pragma unroll
  for (int i = 0; i < 4; i++) {
#pragma unroll
    for (int r = 0; r < 4; r++) {
      int q = i * 16 + fg * 4 + r;
      float vals[4];
      float rowm = -1e30f;
#pragma unroll
      for (int j = 0; j < 4; j++) {
        int kk = j * 16 + fr;
        float v = -1e30f;
        if (q < TOK && kk < TOK) v = s[i][j][r] * scale + bh[q * TOK + kk];
        vals[j] = v;
        rowm = fmaxf(rowm, v);
      }
#pragma unroll
      for (int md = 1; md < 16; md <<= 1) rowm = fmaxf(rowm, __shfl_xor(rowm, md, 64));
      float rs = 0.f;
#pragma unroll
      for (int j = 0; j < 4; j++) { vals[j] = __expf(vals[j] - rowm); rs += vals[j]; }
#pragma unroll
      for (int md = 1; md < 16; md <<= 1) rs += __shfl_xor(rs, md, 64);
      float iv = 1.0f / rs;
#pragma unroll
      for (int j = 0; j < 4; j++)
        P[wave][q * 72 + j * 16 + fr] = (_Float16)(vals[j] * iv);
    }
  }

  // V fragments (B-operand): scalar gathers, column = n*16+fr, 8 consecutive k rows
  half8 vf[2][2];
#pragma unroll
  for (int n = 0; n < 2; n++)
#pragma unroll
    for (int kx = 0; kx < 2; kx++) {
#pragma unroll
      for (int e = 0; e < 8; e++) {
        int kk = kx * 32 + fg * 8 + e;
        _Float16 vv = (_Float16)0.f;
        if (kk < TOK) vv = base[(size_t)kk * K3 + 768 + n * 16 + fr];
        vf[n][kx][e] = vv;
      }
    }

  f32x4 o[4][2];
#pragma unroll
  for (int i = 0; i < 4; i++)
#pragma unroll
    for (int n = 0; n < 2; n++) o[i][n] = (f32x4){0.f, 0.f, 0.f, 0.f};
#pragma unroll
  for (int i = 0; i < 4; i++) {
    half8 pf0 = *(const half8*)(&P[wave][(i * 16 + fr) * 72 + fg * 8]);
    half8 pf1 = *(const half8*)(&P[wave][(i * 16 + fr) * 72 + 32 + fg * 8]);
#pragma unroll
    for (int n = 0; n < 2; n++) {
      o[i][n] = __builtin_amdgcn_mfma_f32_16x16x32_f16(pf0, vf[n][0], o[i][n], 0, 0, 0);
      o[i][n] = __builtin_amdgcn_mfma_f32_16x16x32_f16(pf1, vf[n][1], o[i][n], 0, 0, 0);
    }
  }

  _Float16* obase = aout + (size_t)win * TOK * C_DIM + h * 32;
#pragma unroll
  for (int i = 0; i < 4; i++)
#pragma unroll
    for (int n = 0; n < 2; n++)
#pragma unroll
      for (int r = 0; r < 4; r++) {
        int q = i * 16 + fg * 4 + r;
        if (q < TOK) obase[(size_t)q * C_DIM + n * 16 + fr] = (_Float16)o[i][n][r];
      }
}

extern "C" void kernel_launch(void* const* d_in, const int* in_sizes, int n_in,
                              void* d_out, int out_size, void* d_ws, size_t ws_size,
                              hipStream_t stream) {
  const float* x = (const float*)d_in[0];
  const float* qkv_w = (const float*)d_in[1];
  const float* qkv_b = (const float*)d_in[2];
  const float* proj_w = (const float*)d_in[3];
  const float* proj_b = (const float*)d_in[4];
  const float* rel_table = (const float*)d_in[5];
  const int* rel_index = (const int*)d_in[6];

  char* ws = (char*)d_ws;
  // workspace layout (all 16B aligned), total ~369 MiB
  _Float16* ws_x    = (_Float16*)(ws + 0);            // NTOK*384   fp16: 77,070,336 B
  _Float16* ws_qkv  = (_Float16*)(ws + 77070336);     // NTOK*1152  fp16: 231,211,008 B
  _Float16* ws_attn = (_Float16*)(ws + 308281344);    // NTOK*384   fp16: 77,070,336 B
  _Float16* ws_wT   = (_Float16*)(ws + 385351680);    // 1152*384   fp16
  _Float16* ws_pT   = (_Float16*)(ws + 386236416);    // 384*384    fp16
  float*    ws_bias = (float*)(ws + 386531328);       // 12*49*49   fp32

  cvt_f32_f16<<<37632, 256, 0, stream>>>(x, ws_x, 9633792);
  transpose_to_f16<<<1728, 256, 0, stream>>>(qkv_w, ws_wT, 384, 1152);
  transpose_to_f16<<<576, 256, 0, stream>>>(proj_w, ws_pT, 384, 384);
  bias_expand<<<113, 256, 0, stream>>>(rel_table, rel_index, ws_bias);

  // QKV: M=100352 (784 tiles), N=1152 (9 tiles), K=384
  gemm_f16<0><<<7056, 256, 0, stream>>>(ws_x, ws_wT, qkv_b, ws_qkv, 1152, 384, 9);
  // attention: 2048 windows * 12 heads / 4 waves per block
  win_attn<<<6144, 256, 0, stream>>>(ws_qkv, ws_bias, ws_attn);
  // proj: N=384 (3 tiles), K=384, fp32 out
  gemm_f16<1><<<2352, 256, 0, stream>>>(ws_attn, ws_pT, proj_b, (void*)d_out, 384, 384, 3);
}

// Round 4
// 605.014 us; speedup vs baseline: 1.0044x; 1.0044x over previous
//
#include <hip/hip_runtime.h>
#include <stdint.h>

#define TOK 49
#define NTOK 100352      // 32*3136 tokens
#define K3 1152
#define C_DIM 384
#define NHEAD 12

typedef _Float16 half8 __attribute__((ext_vector_type(8)));
typedef float f32x4 __attribute__((ext_vector_type(4)));

__device__ __forceinline__ ushort f2h_bits(float f) {
  _Float16 h = (_Float16)f;
  return __builtin_bit_cast(ushort, h);
}

__device__ __forceinline__ void gload_lds16(const void* gp, void* lp) {
  __builtin_amdgcn_global_load_lds(
      (const __attribute__((address_space(1))) void*)gp,
      (__attribute__((address_space(3))) void*)lp, 16, 0, 0);
}

// ---------------- x fp32 -> fp16 ----------------
__global__ __launch_bounds__(256) void cvt_f32_f16(const float* __restrict__ in,
                                                   _Float16* __restrict__ out, int n4) {
  int i = blockIdx.x * 256 + threadIdx.x;
  if (i >= n4) return;
  float4 v = *((const float4*)in + i);
  ushort4 o;
  o.x = f2h_bits(v.x); o.y = f2h_bits(v.y); o.z = f2h_bits(v.z); o.w = f2h_bits(v.w);
  *((ushort4*)out + i) = o;
}

// ---------------- W [R][Cc] fp32 -> W^T [Cc][R] fp16 ----------------
__global__ __launch_bounds__(256) void transpose_to_f16(const float* __restrict__ in,
                                                        _Float16* __restrict__ out,
                                                        int R, int Cc) {
  int idx = blockIdx.x * 256 + threadIdx.x;
  if (idx >= R * Cc) return;
  int n = idx / R, k = idx - n * R;
  out[idx] = (_Float16)in[(size_t)k * Cc + n];
}

// ---------------- bias[h][q][k] = table[relidx[q][k]][h] ----------------
__global__ __launch_bounds__(256) void bias_expand(const float* __restrict__ table,
                                                   const int* __restrict__ relidx,
                                                   float* __restrict__ out) {
  int idx = blockIdx.x * 256 + threadIdx.x;
  if (idx >= NHEAD * TOK * TOK) return;
  int h = idx / (TOK * TOK);
  int qk = idx - h * (TOK * TOK);
  out[idx] = table[relidx[qk] * NHEAD + h];
}

// ---------------- GEMM: C[M][N] = A[M][K] @ Bt[N][K]^T + bias ----------------
// 128x128 tile, BK=32, 256 thr (4 waves 2x2), double-buffered 2-phase K-loop.
template <int OUT_F32>
__global__ __launch_bounds__(256) void gemm_f16(const _Float16* __restrict__ A,
                                                const _Float16* __restrict__ Bt,
                                                const float* __restrict__ bias,
                                                void* __restrict__ Cout,
                                                int N, int K, int Ntiles) {
  __shared__ _Float16 As[2][128 * 32];
  __shared__ _Float16 Bs[2][128 * 32];
  int bid = blockIdx.x;
  int bm = bid / Ntiles, bn = bid - bm * Ntiles;
  int tid = threadIdx.x;
  int lane = tid & 63, wave = tid >> 6;
  int wm = wave >> 1, wn = wave & 1;

  int srow = tid >> 2;            // 0..63 staging row
  int scol = (tid & 3) * 8;       // fp16 col offset
  const _Float16* gA = A + (size_t)(bm * 128 + srow) * K + scol;
  const _Float16* gB = Bt + (size_t)(bn * 128 + srow) * K + scol;

  f32x4 acc[4][4];
#pragma unroll
  for (int m = 0; m < 4; m++)
#pragma unroll
    for (int n = 0; n < 4; n++) acc[m][n] = (f32x4){0.f, 0.f, 0.f, 0.f};

  int fr = lane & 15;
  int fk = (lane >> 4) * 8;
  int nk = K >> 5;

  auto STAGE = [&](int buf, int k0) {
    char* la = (char*)As[buf] + wave * 1024;
    char* lb = (char*)Bs[buf] + wave * 1024;
    gload_lds16(gA + k0, la);
    gload_lds16(gA + (size_t)64 * K + k0, la + 4096);
    gload_lds16(gB + k0, lb);
    gload_lds16(gB + (size_t)64 * K + k0, lb + 4096);
  };

  STAGE(0, 0);
  asm volatile("s_waitcnt vmcnt(0)" ::: "memory");
  __builtin_amdgcn_s_barrier();

  for (int t = 0; t < nk; t++) {
    int cur = t & 1;
    if (t + 1 < nk) STAGE(cur ^ 1, (t + 1) * 32);
    half8 af[4], bf[4];
#pragma unroll
    for (int m = 0; m < 4; m++)
      af[m] = *(const half8*)(As[cur] + (wm * 64 + m * 16 + fr) * 32 + fk);
#pragma unroll
    for (int n = 0; n < 4; n++)
      bf[n] = *(const half8*)(Bs[cur] + (wn * 64 + n * 16 + fr) * 32 + fk);
#pragma unroll
    for (int m = 0; m < 4; m++)
#pragma unroll
      for (int n = 0; n < 4; n++)
        acc[m][n] = __builtin_amdgcn_mfma_f32_16x16x32_f16(af[m], bf[n], acc[m][n], 0, 0, 0);
    if (t + 1 < nk) {
      asm volatile("s_waitcnt vmcnt(0)" ::: "memory");
      __builtin_amdgcn_s_barrier();
    }
  }

  int rowbase = bm * 128 + wm * 64;
  int colbase = bn * 128 + wn * 64;
#pragma unroll
  for (int n = 0; n < 4; n++) {
    int col = colbase + n * 16 + fr;
    float bb = bias[col];
#pragma unroll
    for (int m = 0; m < 4; m++) {
      int row0 = rowbase + m * 16 + (lane >> 4) * 4;
#pragma unroll
      for (int r = 0; r < 4; r++) {
        float v = acc[m][n][r] + bb;
        if (OUT_F32)
          ((float*)Cout)[(size_t)(row0 + r) * N + col] = v;
        else
          ((ushort*)Cout)[(size_t)(row0 + r) * N + col] = f2h_bits(v);
      }
    }
  }
}

// ---------------- window attention: 1 wave per (window, head) ----------------
__global__ __launch_bounds__(256) void win_attn(const _Float16* __restrict__ qkv,
                                                const float* __restrict__ biasf,
                                                _Float16* __restrict__ aout) {
  __shared__ _Float16 P[4][64 * 72];   // per-wave P tile, padded stride 72
  int lane = threadIdx.x & 63, wave = threadIdx.x >> 6;
  int id = blockIdx.x * 4 + wave;      // 0..24575
  int win = id / NHEAD;
  int h = id - win * NHEAD;
  const _Float16* base = qkv + (size_t)win * TOK * K3 + h * 32;
  int fr = lane & 15, fg = lane >> 4;

  // V fragments (B-operand) issued FIRST: latency hides under QK^T + softmax.
  half8 vf[2][2];
#pragma unroll
  for (int n = 0; n < 2; n++)
#pragma unroll
    for (int kx = 0; kx < 2; kx++) {
#pragma unroll
      for (int e = 0; e < 8; e++) {
        int kk = kx * 32 + fg * 8 + e;
        _Float16 vv = (_Float16)0.f;
        if (kk < TOK) vv = base[(size_t)kk * K3 + 768 + n * 16 + fr];
        vf[n][kx][e] = vv;
      }
    }

  // Q/K fragments straight from global (row = fr within 16-tile, 8 contig k)
  half8 qf[4], kf[4];
#pragma unroll
  for (int i = 0; i < 4; i++) {
    int q = i * 16 + fr;
    qf[i] = (half8){0, 0, 0, 0, 0, 0, 0, 0};
    kf[i] = (half8){0, 0, 0, 0, 0, 0, 0, 0};
    if (q < TOK) {
      qf[i] = *(const half8*)(base + (size_t)q * K3 + fg * 8);
      kf[i] = *(const half8*)(base + (size_t)q * K3 + 384 + fg * 8);
    }
  }

  f32x4 s[4][4];
#pragma unroll
  for (int i = 0; i < 4; i++)
#pragma unroll
    for (int j = 0; j < 4; j++) s[i][j] = (f32x4){0.f, 0.f, 0.f, 0.f};
#pragma unroll
  for (int i = 0; i < 4; i++)
#pragma unroll
    for (int j = 0; j < 4; j++)
      s[i][j] = __builtin_amdgcn_mfma_f32_16x16x32_f16(qf[i], kf[j], s[i][j], 0, 0, 0);

  const float scale = 0.17677669529663687f;
  const float* bh = biasf + h * (TOK * TOK);
#pragma unroll
  for (int i = 0; i < 4; i++) {
#pragma unroll
    for (int r = 0; r < 4; r++) {
      int q = i * 16 + fg * 4 + r;
      float vals[4];
      float rowm = -1e30f;
#pragma unroll
      for (int j = 0; j < 4; j++) {
        int kk = j * 16 + fr;
        float v = -1e30f;
        if (q < TOK && kk < TOK) v = s[i][j][r] * scale + bh[q * TOK + kk];
        vals[j] = v;
        rowm = fmaxf(rowm, v);
      }
#pragma unroll
      for (int md = 1; md < 16; md <<= 1) rowm = fmaxf(rowm, __shfl_xor(rowm, md, 64));
      float rs = 0.f;
#pragma unroll
      for (int j = 0; j < 4; j++) { vals[j] = __expf(vals[j] - rowm); rs += vals[j]; }
#pragma unroll
      for (int md = 1; md < 16; md <<= 1) rs += __shfl_xor(rs, md, 64);
      float iv = 1.0f / rs;
#pragma unroll
      for (int j = 0; j < 4; j++)
        P[wave][q * 72 + j * 16 + fr] = (_Float16)(vals[j] * iv);
    }
  }

  f32x4 o[4][2];
#pragma unroll
  for (int i = 0; i < 4; i++)
#pragma unroll
    for (int n = 0; n < 2; n++) o[i][n] = (f32x4){0.f, 0.f, 0.f, 0.f};
#pragma unroll
  for (int i = 0; i < 4; i++) {
    half8 pf0 = *(const half8*)(&P[wave][(i * 16 + fr) * 72 + fg * 8]);
    half8 pf1 = *(const half8*)(&P[wave][(i * 16 + fr) * 72 + 32 + fg * 8]);
#pragma unroll
    for (int n = 0; n < 2; n++) {
      o[i][n] = __builtin_amdgcn_mfma_f32_16x16x32_f16(pf0, vf[n][0], o[i][n], 0, 0, 0);
      o[i][n] = __builtin_amdgcn_mfma_f32_16x16x32_f16(pf1, vf[n][1], o[i][n], 0, 0, 0);
    }
  }

  _Float16* obase = aout + (size_t)win * TOK * C_DIM + h * 32;
#pragma unroll
  for (int i = 0; i < 4; i++)
#pragma unroll
    for (int n = 0; n < 2; n++)
#pragma unroll
      for (int r = 0; r < 4; r++) {
        int q = i * 16 + fg * 4 + r;
        if (q < TOK) obase[(size_t)q * C_DIM + n * 16 + fr] = (_Float16)o[i][n][r];
      }
}

extern "C" void kernel_launch(void* const* d_in, const int* in_sizes, int n_in,
                              void* d_out, int out_size, void* d_ws, size_t ws_size,
                              hipStream_t stream) {
  const float* x = (const float*)d_in[0];
  const float* qkv_w = (const float*)d_in[1];
  const float* qkv_b = (const float*)d_in[2];
  const float* proj_w = (const float*)d_in[3];
  const float* proj_b = (const float*)d_in[4];
  const float* rel_table = (const float*)d_in[5];
  const int* rel_index = (const int*)d_in[6];

  char* ws = (char*)d_ws;
  _Float16* ws_x    = (_Float16*)(ws + 0);            // NTOK*384   fp16
  _Float16* ws_qkv  = (_Float16*)(ws + 77070336);     // NTOK*1152  fp16
  _Float16* ws_attn = (_Float16*)(ws + 308281344);    // NTOK*384   fp16
  _Float16* ws_wT   = (_Float16*)(ws + 385351680);    // 1152*384   fp16
  _Float16* ws_pT   = (_Float16*)(ws + 386236416);    // 384*384    fp16
  float*    ws_bias = (float*)(ws + 386531328);       // 12*49*49   fp32

  cvt_f32_f16<<<37632, 256, 0, stream>>>(x, ws_x, 9633792);
  transpose_to_f16<<<1728, 256, 0, stream>>>(qkv_w, ws_wT, 384, 1152);
  transpose_to_f16<<<576, 256, 0, stream>>>(proj_w, ws_pT, 384, 384);
  bias_expand<<<113, 256, 0, stream>>>(rel_table, rel_index, ws_bias);

  gemm_f16<0><<<7056, 256, 0, stream>>>(ws_x, ws_wT, qkv_b, ws_qkv, 1152, 384, 9);
  win_attn<<<6144, 256, 0, stream>>>(ws_qkv, ws_bias, ws_attn);
  gemm_f16<1><<<2352, 256, 0, stream>>>(ws_attn, ws_pT, proj_b, (void*)d_out, 384, 384, 3);
}

// Round 5
// 603.024 us; speedup vs baseline: 1.0078x; 1.0033x over previous
//
#include <hip/hip_runtime.h>
#include <stdint.h>

#define TOK 49
#define NTOK 100352      // 32*3136 tokens
#define K3 1152
#define C_DIM 384
#define NHEAD 12

typedef _Float16 half8 __attribute__((ext_vector_type(8)));
typedef float f32x4 __attribute__((ext_vector_type(4)));

__device__ __forceinline__ ushort f2h_bits(float f) {
  _Float16 h = (_Float16)f;
  return __builtin_bit_cast(ushort, h);
}

__device__ __forceinline__ void gload_lds16(const void* gp, void* lp) {
  __builtin_amdgcn_global_load_lds(
      (const __attribute__((address_space(1))) void*)gp,
      (__attribute__((address_space(3))) void*)lp, 16, 0, 0);
}

// ---------------- x fp32 -> fp16 ----------------
__global__ __launch_bounds__(256) void cvt_f32_f16(const float* __restrict__ in,
                                                   _Float16* __restrict__ out, int n4) {
  int i = blockIdx.x * 256 + threadIdx.x;
  if (i >= n4) return;
  float4 v = *((const float4*)in + i);
  ushort4 o;
  o.x = f2h_bits(v.x); o.y = f2h_bits(v.y); o.z = f2h_bits(v.z); o.w = f2h_bits(v.w);
  *((ushort4*)out + i) = o;
}

// ---------------- W [R][Cc] fp32 -> W^T [Cc][R] fp16 ----------------
__global__ __launch_bounds__(256) void transpose_to_f16(const float* __restrict__ in,
                                                        _Float16* __restrict__ out,
                                                        int R, int Cc) {
  int idx = blockIdx.x * 256 + threadIdx.x;
  if (idx >= R * Cc) return;
  int n = idx / R, k = idx - n * R;
  out[idx] = (_Float16)in[(size_t)k * Cc + n];
}

// ---------------- bias[h][q][k] = table[relidx[q][k]][h] ----------------
__global__ __launch_bounds__(256) void bias_expand(const float* __restrict__ table,
                                                   const int* __restrict__ relidx,
                                                   float* __restrict__ out) {
  int idx = blockIdx.x * 256 + threadIdx.x;
  if (idx >= NHEAD * TOK * TOK) return;
  int h = idx / (TOK * TOK);
  int qk = idx - h * (TOK * TOK);
  out[idx] = table[relidx[qk] * NHEAD + h];
}

// ---------------- GEMM: C[M][N] = A[M][K] @ Bt[N][K]^T + bias ----------------
// 128x128 tile, BK=32, 256 thr (4 waves 2x2).
// Depth-2 pipeline: 3 LDS buffers, counted vmcnt(4), XCD-chunked bid swizzle.
template <int OUT_F32>
__global__ __launch_bounds__(256) void gemm_f16(const _Float16* __restrict__ A,
                                                const _Float16* __restrict__ Bt,
                                                const float* __restrict__ bias,
                                                void* __restrict__ Cout,
                                                int N, int K, int Ntiles) {
  __shared__ _Float16 As[3][128 * 32];
  __shared__ _Float16 Bs[3][128 * 32];
  // XCD-chunked swizzle: grid is a multiple of 8; blocks sharing an A-panel
  // (consecutive bn) land on the same XCD's L2.
  int nchunk = gridDim.x >> 3;
  int bid = (blockIdx.x & 7) * nchunk + (blockIdx.x >> 3);
  int bm = bid / Ntiles, bn = bid - bm * Ntiles;
  int tid = threadIdx.x;
  int lane = tid & 63, wave = tid >> 6;
  int wm = wave >> 1, wn = wave & 1;

  int srow = tid >> 2;            // 0..63 staging row
  int scol = (tid & 3) * 8;       // fp16 col offset
  const _Float16* gA = A + (size_t)(bm * 128 + srow) * K + scol;
  const _Float16* gB = Bt + (size_t)(bn * 128 + srow) * K + scol;

  f32x4 acc[4][4];
#pragma unroll
  for (int m = 0; m < 4; m++)
#pragma unroll
    for (int n = 0; n < 4; n++) acc[m][n] = (f32x4){0.f, 0.f, 0.f, 0.f};

  int fr = lane & 15;
  int fk = (lane >> 4) * 8;
  int nk = K >> 5;                // 12 for K=384

  auto STAGE = [&](int buf, int k0) {
    char* la = (char*)As[buf] + wave * 1024;
    char* lb = (char*)Bs[buf] + wave * 1024;
    gload_lds16(gA + k0, la);
    gload_lds16(gA + (size_t)64 * K + k0, la + 4096);
    gload_lds16(gB + k0, lb);
    gload_lds16(gB + (size_t)64 * K + k0, lb + 4096);
  };

  // prologue: two stages in flight (per-wave 8 outstanding vmem ops)
  STAGE(0, 0);
  STAGE(1, 32);

  int cur = 0;
  for (int t = 0; t < nk; t++) {
    // need stage t complete; leave stage t+1 (4 loads) in flight
    if (t + 1 < nk) asm volatile("s_waitcnt vmcnt(4)" ::: "memory");
    else            asm volatile("s_waitcnt vmcnt(0)" ::: "memory");
    __builtin_amdgcn_s_barrier();
    asm volatile("" ::: "memory");  // keep STAGE/ds_read below the barrier
    if (t + 2 < nk) {
      int nb = cur + 2; if (nb >= 3) nb -= 3;   // == (t-1)%3, freed by this barrier
      STAGE(nb, (t + 2) * 32);
    }
    half8 af[4], bf[4];
#pragma unroll
    for (int m = 0; m < 4; m++)
      af[m] = *(const half8*)(As[cur] + (wm * 64 + m * 16 + fr) * 32 + fk);
#pragma unroll
    for (int n = 0; n < 4; n++)
      bf[n] = *(const half8*)(Bs[cur] + (wn * 64 + n * 16 + fr) * 32 + fk);
#pragma unroll
    for (int m = 0; m < 4; m++)
#pragma unroll
      for (int n = 0; n < 4; n++)
        acc[m][n] = __builtin_amdgcn_mfma_f32_16x16x32_f16(af[m], bf[n], acc[m][n], 0, 0, 0);
    cur++; if (cur == 3) cur = 0;
  }

  int rowbase = bm * 128 + wm * 64;
  int colbase = bn * 128 + wn * 64;
#pragma unroll
  for (int n = 0; n < 4; n++) {
    int col = colbase + n * 16 + fr;
    float bb = bias[col];
#pragma unroll
    for (int m = 0; m < 4; m++) {
      int row0 = rowbase + m * 16 + (lane >> 4) * 4;
#pragma unroll
      for (int r = 0; r < 4; r++) {
        float v = acc[m][n][r] + bb;
        if (OUT_F32)
          ((float*)Cout)[(size_t)(row0 + r) * N + col] = v;
        else
          ((ushort*)Cout)[(size_t)(row0 + r) * N + col] = f2h_bits(v);
      }
    }
  }
}

// ---------------- window attention: 1 wave per (window, head) ----------------
__global__ __launch_bounds__(256) void win_attn(const _Float16* __restrict__ qkv,
                                                const float* __restrict__ biasf,
                                                _Float16* __restrict__ aout) {
  __shared__ _Float16 P[4][64 * 72];   // per-wave P tile, padded stride 72
  int lane = threadIdx.x & 63, wave = threadIdx.x >> 6;
  int id = blockIdx.x * 4 + wave;      // 0..24575
  int win = id / NHEAD;
  int h = id - win * NHEAD;
  const _Float16* base = qkv + (size_t)win * TOK * K3 + h * 32;
  int fr = lane & 15, fg = lane >> 4;

  // V fragments (B-operand) issued FIRST: latency hides under QK^T + softmax.
  half8 vf[2][2];
#pragma unroll
  for (int n = 0; n < 2; n++)
#pragma unroll
    for (int kx = 0; kx < 2; kx++) {
#pragma unroll
      for (int e = 0; e < 8; e++) {
        int kk = kx * 32 + fg * 8 + e;
        _Float16 vv = (_Float16)0.f;
        if (kk < TOK) vv = base[(size_t)kk * K3 + 768 + n * 16 + fr];
        vf[n][kx][e] = vv;
      }
    }

  // Q/K fragments straight from global (row = fr within 16-tile, 8 contig k)
  half8 qf[4], kf[4];
#pragma unroll
  for (int i = 0; i < 4; i++) {
    int q = i * 16 + fr;
    qf[i] = (half8){0, 0, 0, 0, 0, 0, 0, 0};
    kf[i] = (half8){0, 0, 0, 0, 0, 0, 0, 0};
    if (q < TOK) {
      qf[i] = *(const half8*)(base + (size_t)q * K3 + fg * 8);
      kf[i] = *(const half8*)(base + (size_t)q * K3 + 384 + fg * 8);
    }
  }

  f32x4 s[4][4];
#pragma unroll
  for (int i = 0; i < 4; i++)
#pragma unroll
    for (int j = 0; j < 4; j++) s[i][j] = (f32x4){0.f, 0.f, 0.f, 0.f};
#pragma unroll
  for (int i = 0; i < 4; i++)
#pragma unroll
    for (int j = 0; j < 4; j++)
      s[i][j] = __builtin_amdgcn_mfma_f32_16x16x32_f16(qf[i], kf[j], s[i][j], 0, 0, 0);

  const float scale = 0.17677669529663687f;
  const float* bh = biasf + h * (TOK * TOK);
#pragma unroll
  for (int i = 0; i < 4; i++) {
#pragma unroll
    for (int r = 0; r < 4; r++) {
      int q = i * 16 + fg * 4 + r;
      float vals[4];
      float rowm = -1e30f;
#pragma unroll
      for (int j = 0; j < 4; j++) {
        int kk = j * 16 + fr;
        float v = -1e30f;
        if (q < TOK && kk < TOK) v = s[i][j][r] * scale + bh[q * TOK + kk];
        vals[j] = v;
        rowm = fmaxf(rowm, v);
      }
#pragma unroll
      for (int md = 1; md < 16; md <<= 1) rowm = fmaxf(rowm, __shfl_xor(rowm, md, 64));
      float rs = 0.f;
#pragma unroll
      for (int j = 0; j < 4; j++) { vals[j] = __expf(vals[j] - rowm); rs += vals[j]; }
#pragma unroll
      for (int md = 1; md < 16; md <<= 1) rs += __shfl_xor(rs, md, 64);
      float iv = 1.0f / rs;
#pragma unroll
      for (int j = 0; j < 4; j++)
        P[wave][q * 72 + j * 16 + fr] = (_Float16)(vals[j] * iv);
    }
  }

  f32x4 o[4][2];
#pragma unroll
  for (int i = 0; i < 4; i++)
#pragma unroll
    for (int n = 0; n < 2; n++) o[i][n] = (f32x4){0.f, 0.f, 0.f, 0.f};
#pragma unroll
  for (int i = 0; i < 4; i++) {
    half8 pf0 = *(const half8*)(&P[wave][(i * 16 + fr) * 72 + fg * 8]);
    half8 pf1 = *(const half8*)(&P[wave][(i * 16 + fr) * 72 + 32 + fg * 8]);
#pragma unroll
    for (int n = 0; n < 2; n++) {
      o[i][n] = __builtin_amdgcn_mfma_f32_16x16x32_f16(pf0, vf[n][0], o[i][n], 0, 0, 0);
      o[i][n] = __builtin_amdgcn_mfma_f32_16x16x32_f16(pf1, vf[n][1], o[i][n], 0, 0, 0);
    }
  }

  _Float16* obase = aout + (size_t)win * TOK * C_DIM + h * 32;
#pragma unroll
  for (int i = 0; i < 4; i++)
#pragma unroll
    for (int n = 0; n < 2; n++)
#pragma unroll
      for (int r = 0; r < 4; r++) {
        int q = i * 16 + fg * 4 + r;
        if (q < TOK) obase[(size_t)q * C_DIM + n * 16 + fr] = (_Float16)o[i][n][r];
      }
}

extern "C" void kernel_launch(void* const* d_in, const int* in_sizes, int n_in,
                              void* d_out, int out_size, void* d_ws, size_t ws_size,
                              hipStream_t stream) {
  const float* x = (const float*)d_in[0];
  const float* qkv_w = (const float*)d_in[1];
  const float* qkv_b = (const float*)d_in[2];
  const float* proj_w = (const float*)d_in[3];
  const float* proj_b = (const float*)d_in[4];
  const float* rel_table = (const float*)d_in[5];
  const int* rel_index = (const int*)d_in[6];

  char* ws = (char*)d_ws;
  _Float16* ws_x    = (_Float16*)(ws + 0);            // NTOK*384   fp16
  _Float16* ws_qkv  = (_Float16*)(ws + 77070336);     // NTOK*1152  fp16
  _Float16* ws_attn = (_Float16*)(ws + 308281344);    // NTOK*384   fp16
  _Float16* ws_wT   = (_Float16*)(ws + 385351680);    // 1152*384   fp16
  _Float16* ws_pT   = (_Float16*)(ws + 386236416);    // 384*384    fp16
  float*    ws_bias = (float*)(ws + 386531328);       // 12*49*49   fp32

  cvt_f32_f16<<<37632, 256, 0, stream>>>(x, ws_x, 9633792);
  transpose_to_f16<<<1728, 256, 0, stream>>>(qkv_w, ws_wT, 384, 1152);
  transpose_to_f16<<<576, 256, 0, stream>>>(proj_w, ws_pT, 384, 384);
  bias_expand<<<113, 256, 0, stream>>>(rel_table, rel_index, ws_bias);

  // QKV: 7056 blocks = 8 * 882 (swizzle-safe)
  gemm_f16<0><<<7056, 256, 0, stream>>>(ws_x, ws_wT, qkv_b, ws_qkv, 1152, 384, 9);
  win_attn<<<6144, 256, 0, stream>>>(ws_qkv, ws_bias, ws_attn);
  // proj: 2352 blocks = 8 * 294 (swizzle-safe)
  gemm_f16<1><<<2352, 256, 0, stream>>>(ws_attn, ws_pT, proj_b, (void*)d_out, 384, 384, 3);
}